// Round 5
// baseline (594.944 us; speedup 1.0000x reference)
//
#include <hip/hip_runtime.h>
#include <cstdint>

// Embedding gather + int4-group dequant:
//   out[t, d] = (q[x[t], d] - zero[x[t], d/128]) * scale[x[t], d/128]
// T = 16384 tokens, DIM = 1024 (int32-widened by harness), NGROUPS = 8.
//
// Round-4: identical to round-3 submission — that round died on
// GPUAcquisitionTimeout (broker at capacity), kernel never executed.
//
// Layout: one 64-lane wave per token; 4 waves (256 thr) per block.
//   chunk c in 0..3: lane reads 16B at elements (c*64+lane)*4 (1KB/wave
//   contiguous); group g = c*2 + (lane>>5). Nontemporal stores (out is
//   never re-read; keep L2/L3 for the weight table).

#define EMB_DIM 1024
#define EMB_NGROUPS 8

typedef float f32x4 __attribute__((ext_vector_type(4)));
typedef int   i32x4 __attribute__((ext_vector_type(4)));

__global__ __launch_bounds__(256) void deq_embed_kernel(
    const int*   __restrict__ qvals,   // [NUM_EMB, 1024] int32 (int4 values)
    const float* __restrict__ scales,  // [NUM_EMB, 8] fp32
    const int*   __restrict__ zeros,   // [NUM_EMB, 8] int32
    const int*   __restrict__ x,       // [T] int32
    float*       __restrict__ out,     // [T, 1024] fp32
    int T)
{
    const int wave  = threadIdx.x >> 6;              // 0..3 within block
    const int lane  = threadIdx.x & 63;
    const int token = (blockIdx.x << 2) + wave;      // wave-per-token
    if (token >= T) return;

    const int row = x[token];                        // wave-uniform (HW broadcast)

    const i32x4* src = reinterpret_cast<const i32x4*>(qvals + (size_t)row * EMB_DIM) + lane;
    f32x4*       dst = reinterpret_cast<f32x4*>(out + (size_t)token * EMB_DIM) + lane;
    const float* srow = scales + (size_t)row * EMB_NGROUPS;
    const int*   zrow = zeros  + (size_t)row * EMB_NGROUPS;

    #pragma unroll
    for (int c = 0; c < 4; ++c) {
        // elements covered by this lane: e = (c*64 + lane)*4 ; group = e>>7
        const int g = (c << 1) + (lane >> 5);        // 0..7
        const i32x4 q = src[c * 64];                 // 16B coalesced, 1KB/wave
        const float s = srow[g];
        const float z = (float)zrow[g];

        f32x4 o;
        o.x = ((float)q.x - z) * s;
        o.y = ((float)q.y - z) * s;
        o.z = ((float)q.z - z) * s;
        o.w = ((float)q.w - z) * s;

        __builtin_nontemporal_store(o, dst + c * 64);
    }
}

extern "C" void kernel_launch(void* const* d_in, const int* in_sizes, int n_in,
                              void* d_out, int out_size, void* d_ws, size_t ws_size,
                              hipStream_t stream) {
    const int*   qvals  = (const int*)  d_in[0];
    const float* scales = (const float*)d_in[1];
    const int*   zeros  = (const int*)  d_in[2];
    const int*   x      = (const int*)  d_in[3];
    float*       out    = (float*)      d_out;

    const int T = in_sizes[3];                       // 8 * 2048 = 16384 tokens
    const int blocks = (T + 3) >> 2;                 // 4 tokens (waves) per block

    deq_embed_kernel<<<dim3(blocks), dim3(256), 0, stream>>>(
        qvals, scales, zeros, x, out, T);
}